// Round 1
// baseline (224.756 us; speedup 1.0000x reference)
//
#include <hip/hip_runtime.h>
#include <math.h>

// GCN layer: agg = D^-1/2 (A w) D^-1/2 x + x ; out = LayerNorm(gelu(agg @ W + b))
// N=10000 nodes, E=640000 edges, D=128. All fp32; edge_index as int32.
//
// Strategy: build CSR (edges bucketed by dst) with cheap int atomics, then a
// single fused per-node kernel does atomic-free aggregation + linear + exact
// GELU + LayerNorm. agg is never materialized to HBM.

#define D 128

static __device__ __forceinline__ int imin(int a, int b) { return a < b ? a : b; }

__global__ void count_deg(const int* __restrict__ dstIdx, int* __restrict__ deg, int E) {
    int e = blockIdx.x * blockDim.x + threadIdx.x;
    if (e < E) atomicAdd(&deg[dstIdx[e]], 1);
}

// One block of 1024 threads: exclusive prefix sum of deg[N] -> rowptr[N+1], cursor[N]
__global__ void scan_rowptr(const int* __restrict__ deg, int* __restrict__ rowptr,
                            int* __restrict__ cursor, int N) {
    __shared__ int sums[1024];
    int t = threadIdx.x;
    int chunk = (N + 1023) >> 10;
    int start = t * chunk;
    int end = imin(start + chunk, N);
    int local = 0;
    for (int i = start; i < end; ++i) local += deg[i];
    sums[t] = local;
    __syncthreads();
    // Hillis-Steele inclusive scan over 1024 thread sums
    for (int off = 1; off < 1024; off <<= 1) {
        int v = (t >= off) ? sums[t - off] : 0;
        __syncthreads();
        if (t >= off) sums[t] += v;
        __syncthreads();
    }
    int run = (t > 0) ? sums[t - 1] : 0;  // exclusive base for this chunk
    for (int i = start; i < end; ++i) {
        rowptr[i] = run;
        cursor[i] = run;
        run += deg[i];
    }
    if (end == N && start <= N) rowptr[N] = run;  // total (tail thread(s) write same value)
}

__global__ void scatter_edges(const int* __restrict__ srcIdx, const int* __restrict__ dstIdx,
                              const float* __restrict__ ew, const int* __restrict__ deg,
                              int* __restrict__ cursor, int* __restrict__ srcs,
                              float* __restrict__ wts, int E) {
    int e = blockIdx.x * blockDim.x + threadIdx.x;
    if (e >= E) return;
    int d = dstIdx[e];
    int s = srcIdx[e];
    int pos = atomicAdd(&cursor[d], 1);
    srcs[pos] = s;
    // pre-fold deg_inv[src] * edge_weight into the stored coefficient
    wts[pos] = rsqrtf((float)deg[s] + 1.0f) * ew[e];
}

// One block (128 threads = 2 waves) per node. Thread t owns output feature t.
__global__ __launch_bounds__(128) void fused_node(
    const float* __restrict__ x, const int* __restrict__ rowptr,
    const int* __restrict__ srcs, const float* __restrict__ wts,
    const int* __restrict__ deg, const float* __restrict__ W,
    const float* __restrict__ b, const float* __restrict__ gamma,
    const float* __restrict__ beta, float* __restrict__ out) {
    int node = blockIdx.x;
    int t = threadIdx.x;  // feature index d
    int rs = rowptr[node];
    int re = rowptr[node + 1];

    // --- aggregation: acc = sum_e w_e * x[src_e][t] (coalesced 512B row reads) ---
    float acc = 0.0f;
    int e = rs;
    for (; e + 1 < re; e += 2) {  // 2-edge unroll for MLP
        int s0 = srcs[e], s1 = srcs[e + 1];
        float w0 = wts[e], w1 = wts[e + 1];
        float x0 = x[s0 * D + t];
        float x1 = x[s1 * D + t];
        acc += x0 * w0 + x1 * w1;
    }
    if (e < re) {
        acc += x[srcs[e] * D + t] * wts[e];
    }
    float dinv = rsqrtf((float)deg[node] + 1.0f);
    float aggv = acc * dinv + x[node * D + t];

    __shared__ float agg_s[D];
    agg_s[t] = aggv;
    __syncthreads();

    // --- linear: h = b[t] + sum_k agg_s[k] * W[k][t] (W reads coalesced) ---
    float h = b[t];
#pragma unroll 8
    for (int k = 0; k < D; ++k) {
        h += agg_s[k] * W[k * D + t];
    }

    // --- exact GELU ---
    h = 0.5f * h * (1.0f + erff(h * 0.70710678118654752f));

    // --- LayerNorm over the 128 features of this node ---
    float v1 = h, v2 = h * h;
#pragma unroll
    for (int o = 32; o > 0; o >>= 1) {
        v1 += __shfl_xor(v1, o, 64);
        v2 += __shfl_xor(v2, o, 64);
    }
    __shared__ float s1s[2], s2s[2];
    int wid = t >> 6, lane = t & 63;
    if (lane == 0) { s1s[wid] = v1; s2s[wid] = v2; }
    __syncthreads();
    float s1 = s1s[0] + s1s[1];
    float s2 = s2s[0] + s2s[1];
    float mu = s1 * (1.0f / D);
    float var = s2 * (1.0f / D) - mu * mu;
    float r = rsqrtf(var + 1e-5f);
    out[node * D + t] = (h - mu) * r * gamma[t] + beta[t];
}

static inline size_t align256(size_t v) { return (v + 255) & ~(size_t)255; }

extern "C" void kernel_launch(void* const* d_in, const int* in_sizes, int n_in,
                              void* d_out, int out_size, void* d_ws, size_t ws_size,
                              hipStream_t stream) {
    const float* x     = (const float*)d_in[0];
    const int*   ei    = (const int*)d_in[1];
    const float* ew    = (const float*)d_in[2];
    const float* W     = (const float*)d_in[3];
    const float* b     = (const float*)d_in[4];
    const float* gamma = (const float*)d_in[5];
    const float* beta  = (const float*)d_in[6];
    float* out = (float*)d_out;

    const int E = in_sizes[2];       // 640000
    const int N = in_sizes[0] / D;   // 10000
    const int* srcIdx = ei;          // edge_index[0]
    const int* dstIdx = ei + E;      // edge_index[1]

    char* ws = (char*)d_ws;
    size_t off = 0;
    int* deg = (int*)(ws + off);          off += align256((size_t)N * 4);
    int* rowptr = (int*)(ws + off);       off += align256((size_t)(N + 1) * 4);
    int* cursor = (int*)(ws + off);       off += align256((size_t)N * 4);
    int* srcs = (int*)(ws + off);         off += align256((size_t)E * 4);
    float* wts = (float*)(ws + off);      off += align256((size_t)E * 4);
    (void)ws_size; (void)n_in; (void)out_size;

    hipMemsetAsync(deg, 0, (size_t)N * sizeof(int), stream);
    count_deg<<<(E + 255) / 256, 256, 0, stream>>>(dstIdx, deg, E);
    scan_rowptr<<<1, 1024, 0, stream>>>(deg, rowptr, cursor, N);
    scatter_edges<<<(E + 255) / 256, 256, 0, stream>>>(srcIdx, dstIdx, ew, deg, cursor, srcs, wts, E);
    fused_node<<<N, 128, 0, stream>>>(x, rowptr, srcs, wts, deg, W, b, gamma, beta, out);
}

// Round 2
// 216.880 us; speedup vs baseline: 1.0363x; 1.0363x over previous
//
#include <hip/hip_runtime.h>
#include <math.h>

// GCN layer: agg = D^-1/2 (A w) D^-1/2 x + x ; out = LayerNorm(gelu(agg @ W + b))
// N=10000, E=640000, D=128. fp32 in/out; edge_index int32.
//
// R2: (a) pack CSR payload as one uint2 (src, wt) -> one 8-B random store per
// edge instead of two 4-B stores; (b) gather operand is bf16-packed
// xs = bf16(x * deg_inv) (2.5 MB, L2-resident), 2 features per lane, edges
// split across the block's 2 waves with 4-edge unroll for MLP.

#define D 128

static __device__ __forceinline__ int imin(int a, int b) { return a < b ? a : b; }

// round-to-nearest-even fp32 -> bf16 bits
static __device__ __forceinline__ unsigned int bf16bits(float v) {
    unsigned int u = __float_as_uint(v);
    return (u + 0x7fffu + ((u >> 16) & 1u)) >> 16;
}

__global__ void count_deg(const int* __restrict__ dstIdx, int* __restrict__ deg, int E) {
    int e = blockIdx.x * blockDim.x + threadIdx.x;
    if (e < E) atomicAdd(&deg[dstIdx[e]], 1);
}

// One block of 1024 threads: exclusive prefix sum of deg[N] -> rowptr[N+1], cursor[N]
__global__ void scan_rowptr(const int* __restrict__ deg, int* __restrict__ rowptr,
                            int* __restrict__ cursor, int N) {
    __shared__ int sums[1024];
    int t = threadIdx.x;
    int chunk = (N + 1023) >> 10;
    int start = t * chunk;
    int end = imin(start + chunk, N);
    int local = 0;
    for (int i = start; i < end; ++i) local += deg[i];
    sums[t] = local;
    __syncthreads();
    for (int off = 1; off < 1024; off <<= 1) {
        int v = (t >= off) ? sums[t - off] : 0;
        __syncthreads();
        if (t >= off) sums[t] += v;
        __syncthreads();
    }
    int run = (t > 0) ? sums[t - 1] : 0;
    for (int i = start; i < end; ++i) {
        rowptr[i] = run;
        cursor[i] = run;
        run += deg[i];
    }
    if (end == N && start <= N) rowptr[N] = run;
}

// xs[n][0..63] = packed bf16 pair (x[n][2p]*dinv, x[n][2p+1]*dinv)
__global__ void xscale(const float* __restrict__ x, const int* __restrict__ deg,
                       unsigned int* __restrict__ xs, int N) {
    int idx = blockIdx.x * blockDim.x + threadIdx.x;  // over N*64
    if (idx >= N * 64) return;
    int n = idx >> 6;
    const float2* x2 = (const float2*)x;
    float2 xv = x2[idx];
    float s = rsqrtf((float)deg[n] + 1.0f);
    unsigned int lo = bf16bits(xv.x * s);
    unsigned int hi = bf16bits(xv.y * s);
    xs[idx] = lo | (hi << 16);
}

__global__ void scatter_edges(const int* __restrict__ srcIdx, const int* __restrict__ dstIdx,
                              const float* __restrict__ ew, int* __restrict__ cursor,
                              uint2* __restrict__ edges, int E) {
    int e = blockIdx.x * blockDim.x + threadIdx.x;
    if (e >= E) return;
    int d = dstIdx[e];
    int pos = atomicAdd(&cursor[d], 1);
    edges[pos] = make_uint2((unsigned int)srcIdx[e], __float_as_uint(ew[e]));
}

// One block (128 threads = 2 waves) per node.
// Aggregation: wave w handles edges rs+w, rs+w+2, ...; lane l accumulates
// features 2l, 2l+1 from packed-bf16 xs rows. Then linear+GELU+LN with
// thread t owning output feature t.
__global__ __launch_bounds__(128) void fused_node(
    const float* __restrict__ x, const unsigned int* __restrict__ xs,
    const int* __restrict__ rowptr, const uint2* __restrict__ edges,
    const int* __restrict__ deg, const float* __restrict__ W,
    const float* __restrict__ b, const float* __restrict__ gamma,
    const float* __restrict__ beta, float* __restrict__ out) {
    int node = blockIdx.x;
    int t = threadIdx.x;
    int w = t >> 6;       // wave id 0/1
    int l = t & 63;       // lane
    int rs = rowptr[node];
    int re = rowptr[node + 1];

    float acc0 = 0.0f, acc1 = 0.0f;
    int i = rs + w;
#define EDGE_STEP(ii)                                            \
    {                                                            \
        uint2 ev = edges[(ii)];                                  \
        float wt = __uint_as_float(ev.y);                        \
        unsigned int xp = xs[ev.x * 64u + (unsigned int)l];      \
        float f0 = __uint_as_float(xp << 16);                    \
        float f1 = __uint_as_float(xp & 0xffff0000u);            \
        acc0 = fmaf(f0, wt, acc0);                               \
        acc1 = fmaf(f1, wt, acc1);                               \
    }
    for (; i + 6 < re; i += 8) {
        EDGE_STEP(i); EDGE_STEP(i + 2); EDGE_STEP(i + 4); EDGE_STEP(i + 6);
    }
    for (; i < re; i += 2) { EDGE_STEP(i); }
#undef EDGE_STEP

    __shared__ float part[2][D];
    part[w][2 * l] = acc0;
    part[w][2 * l + 1] = acc1;
    __syncthreads();

    float dinv = rsqrtf((float)deg[node] + 1.0f);
    float aggv = (part[0][t] + part[1][t]) * dinv + x[node * D + t];

    __shared__ float agg_s[D];
    agg_s[t] = aggv;
    __syncthreads();

    float h = b[t];
#pragma unroll 8
    for (int k = 0; k < D; ++k) {
        h += agg_s[k] * W[k * D + t];
    }

    h = 0.5f * h * (1.0f + erff(h * 0.70710678118654752f));

    float v1 = h, v2 = h * h;
#pragma unroll
    for (int o = 32; o > 0; o >>= 1) {
        v1 += __shfl_xor(v1, o, 64);
        v2 += __shfl_xor(v2, o, 64);
    }
    __shared__ float s1s[2], s2s[2];
    if (l == 0) { s1s[w] = v1; s2s[w] = v2; }
    __syncthreads();
    float s1 = s1s[0] + s1s[1];
    float s2 = s2s[0] + s2s[1];
    float mu = s1 * (1.0f / D);
    float var = s2 * (1.0f / D) - mu * mu;
    float r = rsqrtf(var + 1e-5f);
    out[node * D + t] = (h - mu) * r * gamma[t] + beta[t];
}

static inline size_t align256(size_t v) { return (v + 255) & ~(size_t)255; }

extern "C" void kernel_launch(void* const* d_in, const int* in_sizes, int n_in,
                              void* d_out, int out_size, void* d_ws, size_t ws_size,
                              hipStream_t stream) {
    const float* x     = (const float*)d_in[0];
    const int*   ei    = (const int*)d_in[1];
    const float* ew    = (const float*)d_in[2];
    const float* W     = (const float*)d_in[3];
    const float* b     = (const float*)d_in[4];
    const float* gamma = (const float*)d_in[5];
    const float* beta  = (const float*)d_in[6];
    float* out = (float*)d_out;

    const int E = in_sizes[2];       // 640000
    const int N = in_sizes[0] / D;   // 10000
    const int* srcIdx = ei;
    const int* dstIdx = ei + E;

    char* ws = (char*)d_ws;
    size_t off = 0;
    int* deg = (int*)(ws + off);            off += align256((size_t)N * 4);
    int* rowptr = (int*)(ws + off);         off += align256((size_t)(N + 1) * 4);
    int* cursor = (int*)(ws + off);         off += align256((size_t)N * 4);
    uint2* edges = (uint2*)(ws + off);      off += align256((size_t)E * 8);
    unsigned int* xs = (unsigned int*)(ws + off); off += align256((size_t)N * 64 * 4);
    (void)ws_size; (void)n_in; (void)out_size;

    hipMemsetAsync(deg, 0, (size_t)N * sizeof(int), stream);
    count_deg<<<(E + 255) / 256, 256, 0, stream>>>(dstIdx, deg, E);
    scan_rowptr<<<1, 1024, 0, stream>>>(deg, rowptr, cursor, N);
    xscale<<<(N * 64 + 255) / 256, 256, 0, stream>>>(x, deg, xs, N);
    scatter_edges<<<(E + 255) / 256, 256, 0, stream>>>(srcIdx, dstIdx, ew, cursor, edges, E);
    fused_node<<<N, 128, 0, stream>>>(x, xs, rowptr, edges, deg, W, b, gamma, beta, out);
}

// Round 3
// 150.015 us; speedup vs baseline: 1.4982x; 1.4457x over previous
//
#include <hip/hip_runtime.h>
#include <math.h>

// GCN layer: agg = D^-1/2 (A w) D^-1/2 x + x ; out = LayerNorm(gelu(agg @ W + b))
// N=10000, E=640000, D=128. fp32 in/out; edge_index int32.
//
// R3: CSR build via two-level counting sort on dst (bucket = dst>>6):
//   bucket_count (LDS hist, ~40k global atomics) -> bucket_scan (1 block)
//   -> bucket_scatter (per-block reserved sub-ranges, clustered 8-B writes)
//   -> bucket_to_csr (per-bucket block: exact rowptr + deginv + 4-B payload
//      src|bf16(ew), contiguous reads/writes, LDS cursors only).
// fused: 2 nodes per 256-thr block (W L1 reuse), 8-edge unroll per wave,
// 4-B edge payload, bf16 xs gathers (2 feats/lane).

#define D 128
#define NB_MAX 256   // max buckets (N <= 16384)

static __device__ __forceinline__ unsigned int bf16bits(float v) {
    unsigned int u = __float_as_uint(v);
    return (u + 0x7fffu + ((u >> 16) & 1u)) >> 16;
}

// --- K1: per-bucket edge counts (bucket = dst>>6) ---
__global__ __launch_bounds__(256) void bucket_count(const int* __restrict__ dstIdx,
                                                    int* __restrict__ bucketcnt, int E) {
    __shared__ int hist[NB_MAX];
    int t = threadIdx.x;
    hist[t] = 0;
    __syncthreads();
    for (int e = blockIdx.x * 256 + t; e < E; e += gridDim.x * 256)
        atomicAdd(&hist[dstIdx[e] >> 6], 1);
    __syncthreads();
    if (hist[t]) atomicAdd(&bucketcnt[t], hist[t]);
}

// --- K2: exclusive scan of bucket counts -> bucketptr[257], bucketcur ---
__global__ __launch_bounds__(256) void bucket_scan(const int* __restrict__ bucketcnt,
                                                   int* __restrict__ bucketptr,
                                                   int* __restrict__ bucketcur) {
    __shared__ int s[NB_MAX];
    int t = threadIdx.x;
    int v = bucketcnt[t];
    s[t] = v;
    __syncthreads();
    for (int o = 1; o < NB_MAX; o <<= 1) {
        int n = (t >= o) ? s[t - o] : 0;
        __syncthreads();
        if (t >= o) s[t] += n;
        __syncthreads();
    }
    int incl = s[t];
    bucketptr[t + 1] = incl;
    if (t == 0) bucketptr[0] = 0;
    bucketcur[t] = incl - v;  // exclusive base
}

// --- K3: scatter edges into bucket regions (8-B records, clustered writes) ---
__global__ __launch_bounds__(256) void bucket_scatter(const int* __restrict__ srcIdx,
                                                      const int* __restrict__ dstIdx,
                                                      const float* __restrict__ ew,
                                                      int* __restrict__ bucketcur,
                                                      uint2* __restrict__ tmp, int E) {
    __shared__ int hist[NB_MAX];
    __shared__ int base[NB_MAX];
    int t = threadIdx.x;
    hist[t] = 0;
    __syncthreads();
    int stride = gridDim.x * 256;
    for (int e = blockIdx.x * 256 + t; e < E; e += stride)
        atomicAdd(&hist[dstIdx[e] >> 6], 1);
    __syncthreads();
    int c = hist[t];
    base[t] = c ? atomicAdd(&bucketcur[t], c) : 0;  // reserve contiguous sub-range
    hist[t] = 0;                                    // becomes running cursor
    __syncthreads();
    for (int e = blockIdx.x * 256 + t; e < E; e += stride) {
        int d = dstIdx[e];
        int bkt = d >> 6;
        int off = atomicAdd(&hist[bkt], 1);
        tmp[base[bkt] + off] = make_uint2((unsigned)srcIdx[e] | ((unsigned)(d & 63) << 16),
                                          __float_as_uint(ew[e]));
    }
}

// --- K4: per-bucket local sort -> final CSR payload + rowptr + deginv ---
__global__ __launch_bounds__(256) void bucket_to_csr(const uint2* __restrict__ tmp,
                                                     const int* __restrict__ bucketptr,
                                                     unsigned int* __restrict__ fin,
                                                     int* __restrict__ rowptr,
                                                     float* __restrict__ deginv,
                                                     int N, int E) {
    __shared__ int cnt[64];
    __shared__ int cur[64];
    int b = blockIdx.x;
    int t = threadIdx.x;
    int s = bucketptr[b], e2 = bucketptr[b + 1];
    if (t < 64) cnt[t] = 0;
    __syncthreads();
    for (int i = s + t; i < e2; i += 256)
        atomicAdd(&cnt[(tmp[i].x >> 16) & 63], 1);
    __syncthreads();
    if (t < 64) {  // wave 0: 64-wide shfl scan of per-dst counts
        int v = cnt[t];
        int incl = v;
        for (int o = 1; o < 64; o <<= 1) {
            int n = __shfl_up(incl, o, 64);
            if (t >= o) incl += n;
        }
        int excl = incl - v;
        int d = (b << 6) + t;
        if (d < N) {
            rowptr[d] = s + excl;
            deginv[d] = rsqrtf((float)v + 1.0f);
            if (d == N - 1) rowptr[N] = E;
        }
        cur[t] = s + excl;
    }
    __syncthreads();
    for (int i = s + t; i < e2; i += 256) {
        uint2 v = tmp[i];
        int dl = (v.x >> 16) & 63;
        int pos = atomicAdd(&cur[dl], 1);
        fin[pos] = (v.x & 0xffffu) | (bf16bits(__uint_as_float(v.y)) << 16);
    }
}

// --- K5: xs[n] = packed bf16 pairs of x[n] * deginv[n] ---
__global__ __launch_bounds__(256) void xscale(const float* __restrict__ x,
                                              const float* __restrict__ deginv,
                                              unsigned int* __restrict__ xs, int N64) {
    int idx = blockIdx.x * 256 + threadIdx.x;
    if (idx >= N64) return;
    float2 xv = ((const float2*)x)[idx];
    float sc = deginv[idx >> 6];
    xs[idx] = bf16bits(xv.x * sc) | (bf16bits(xv.y * sc) << 16);
}

// --- K6: fused aggregation + linear + GELU + LayerNorm. 2 nodes / block. ---
__global__ __launch_bounds__(256) void fused_node(
    const float* __restrict__ x, const unsigned int* __restrict__ xs,
    const int* __restrict__ rowptr, const unsigned int* __restrict__ fin,
    const float* __restrict__ deginv, const float* __restrict__ W,
    const float* __restrict__ bias, const float* __restrict__ gamma,
    const float* __restrict__ beta, float* __restrict__ out, int N) {
    int t = threadIdx.x;
    int nh = t >> 7;        // which of the block's 2 nodes
    int tt = t & 127;       // feature
    int w = (t >> 6) & 1;   // wave within node
    int l = t & 63;         // lane
    int node = blockIdx.x * 2 + nh;
    bool valid = node < N;
    int rs = 0, re = 0;
    if (valid) { rs = rowptr[node]; re = rowptr[node + 1]; }

    float acc0 = 0.0f, acc1 = 0.0f;
    int i = rs + w;
#define ESTEP(ii)                                                      \
    {                                                                  \
        unsigned p = fin[(ii)];                                        \
        float wt = __uint_as_float(p & 0xffff0000u);                   \
        unsigned xp = xs[(p & 0xffffu) * 64u + (unsigned)l];           \
        acc0 = fmaf(__uint_as_float(xp << 16), wt, acc0);              \
        acc1 = fmaf(__uint_as_float(xp & 0xffff0000u), wt, acc1);      \
    }
    for (; i + 14 < re; i += 16) {
        ESTEP(i) ESTEP(i + 2) ESTEP(i + 4) ESTEP(i + 6)
        ESTEP(i + 8) ESTEP(i + 10) ESTEP(i + 12) ESTEP(i + 14)
    }
    for (; i < re; i += 2) ESTEP(i)
#undef ESTEP

    __shared__ float part[2][2][D];
    part[nh][w][2 * l] = acc0;
    part[nh][w][2 * l + 1] = acc1;
    __syncthreads();

    __shared__ float agg_s[2][D];
    float aggv = 0.0f;
    if (valid) aggv = (part[nh][0][tt] + part[nh][1][tt]) * deginv[node] + x[node * D + tt];
    agg_s[nh][tt] = aggv;
    __syncthreads();

    float h = bias[tt];
#pragma unroll 8
    for (int k = 0; k < D; ++k)
        h = fmaf(agg_s[nh][k], W[k * D + tt], h);

    h = 0.5f * h * (1.0f + erff(h * 0.70710678118654752f));

    float v1 = h, v2 = h * h;
#pragma unroll
    for (int o = 32; o > 0; o >>= 1) {
        v1 += __shfl_xor(v1, o, 64);
        v2 += __shfl_xor(v2, o, 64);
    }
    __shared__ float s1s[2][2], s2s[2][2];
    if (l == 0) { s1s[nh][w] = v1; s2s[nh][w] = v2; }
    __syncthreads();
    float s1 = s1s[nh][0] + s1s[nh][1];
    float s2 = s2s[nh][0] + s2s[nh][1];
    float mu = s1 * (1.0f / D);
    float var = s2 * (1.0f / D) - mu * mu;
    float r = rsqrtf(var + 1e-5f);
    if (valid) out[node * D + tt] = (h - mu) * r * gamma[tt] + beta[tt];
}

static inline size_t align256(size_t v) { return (v + 255) & ~(size_t)255; }

extern "C" void kernel_launch(void* const* d_in, const int* in_sizes, int n_in,
                              void* d_out, int out_size, void* d_ws, size_t ws_size,
                              hipStream_t stream) {
    const float* x     = (const float*)d_in[0];
    const int*   ei    = (const int*)d_in[1];
    const float* ew    = (const float*)d_in[2];
    const float* W     = (const float*)d_in[3];
    const float* b     = (const float*)d_in[4];
    const float* gamma = (const float*)d_in[5];
    const float* beta  = (const float*)d_in[6];
    float* out = (float*)d_out;

    const int E = in_sizes[2];       // 640000
    const int N = in_sizes[0] / D;   // 10000
    const int NB = (N + 63) >> 6;    // 157 buckets
    const int* srcIdx = ei;
    const int* dstIdx = ei + E;

    char* ws = (char*)d_ws;
    size_t off = 0;
    int* bucketcnt = (int*)(ws + off);      off += align256((size_t)NB_MAX * 4);
    int* bucketptr = (int*)(ws + off);      off += align256((size_t)(NB_MAX + 1) * 4);
    int* bucketcur = (int*)(ws + off);      off += align256((size_t)NB_MAX * 4);
    int* rowptr = (int*)(ws + off);         off += align256((size_t)(N + 1) * 4);
    float* deginv = (float*)(ws + off);     off += align256((size_t)N * 4);
    uint2* tmp = (uint2*)(ws + off);        off += align256((size_t)E * 8);
    unsigned int* fin = (unsigned int*)(ws + off);  off += align256((size_t)E * 4);
    unsigned int* xs = (unsigned int*)(ws + off);   off += align256((size_t)N * 64 * 4);
    (void)ws_size; (void)n_in; (void)out_size;

    hipMemsetAsync(bucketcnt, 0, NB_MAX * sizeof(int), stream);
    bucket_count<<<256, 256, 0, stream>>>(dstIdx, bucketcnt, E);
    bucket_scan<<<1, 256, 0, stream>>>(bucketcnt, bucketptr, bucketcur);
    bucket_scatter<<<128, 256, 0, stream>>>(srcIdx, dstIdx, ew, bucketcur, tmp, E);
    bucket_to_csr<<<NB, 256, 0, stream>>>(tmp, bucketptr, fin, rowptr, deginv, N, E);
    xscale<<<(N * 64 + 255) / 256, 256, 0, stream>>>(x, deginv, xs, N * 64);
    fused_node<<<(N + 1) / 2, 256, 0, stream>>>(x, xs, rowptr, fin, deginv, W, b, gamma, beta, out, N);
}